// Round 15
// baseline (506.574 us; speedup 1.0000x reference)
//
#include <hip/hip_runtime.h>
#include <hip/hip_bf16.h>
#include <math.h>

typedef unsigned short u16;
typedef __attribute__((ext_vector_type(8))) short  bf16x8;
typedef __attribute__((ext_vector_type(4))) float  f32x4;
typedef __attribute__((ext_vector_type(8))) u16    u16x8;
typedef __attribute__((ext_vector_type(4))) u16    u16x4;

// ---------------- problem constants ----------------
#define B_      8
#define NT_     16
#define DIM_    768
#define HEADS_  8
#define HD_     96
#define PIX_    1024
#define NTOK_   1040
#define NPAD_   1152

// ---------------- workspace layout (byte offsets) ----------------
#define WSO_XCB     0ull
#define WSO_WQKV    12779520ull
#define WSO_WPROJ   16318464ull
#define WSO_QB      17498112ull
#define WSO_KB      31653888ull
#define WSO_VB      45809664ull
#define WSO_VTB     59965440ull
#define WSO_ACATB   74121216ull
#define WSO_TPB     86900736ull
#define WSO_TTWB    87097344ull
#define WSO_TT1WB   88670208ull
#define WSO_CHANPB  90243072ull
#define WSO_PART    90505216ull    // (64,9,1152) float2
#define WSO_F32     95813632ull
// fp32 region offsets (floats)
#define FO_TPOUT    0ull           // 98,304
#define FO_RAWCHAN  98304ull       // 1,572,864
#define FO_CHP      1671168ull     // 98,304
#define FO_FE2      1769472ull     // 393,216
#define FO_STATS    2162688ull     // 1024

// ---------------- output layout (float offsets) ----------------
#define OUT_XOUT   0ull
#define OUT_RAW    6291456ull
#define OUT_ATTN   75513856ull
#define OUT_RAWCH  144736256ull
#define OUT_ATTNCH 146309120ull
#define OUT_QOUT   147881984ull

#define SCALE_SPA 0.1020620726159658f   // 96^-0.5

__device__ __forceinline__ u16 f2b(float f) {
    union { float f; unsigned u; } x; x.f = f;
    unsigned r = x.u + 0x7FFFu + ((x.u >> 16) & 1u);
    return (u16)(r >> 16);
}
__device__ __forceinline__ u16 f2b_fast(float f) {
    __hip_bfloat16 h = __float2bfloat16(f);
    return __builtin_bit_cast(u16, h);
}
__device__ __forceinline__ float b2f(u16 h) {
    union { unsigned u; float f; } x; x.u = ((unsigned)h) << 16;
    return x.f;
}

// async global->LDS, 16B per lane, wave-uniform LDS base
__device__ __forceinline__ void gload_lds16(const u16* gsrc, u16* ldst) {
    __builtin_amdgcn_global_load_lds((const __attribute__((address_space(1))) void*)gsrc,
                                     (__attribute__((address_space(3))) void*)ldst,
                                     16, 0, 0);
}

// =================== all casts in one launch (same resource class) ===================
__global__ __launch_bounds__(256) void cast_fused(const float* __restrict__ tp,
                                                  const float* __restrict__ x,
                                                  const float* __restrict__ qkv_w,
                                                  const float* __restrict__ proj_w,
                                                  const float* __restrict__ tt_w,
                                                  const float* __restrict__ tt1_w,
                                                  u16* __restrict__ xcb,
                                                  u16* __restrict__ wqkvb,
                                                  u16* __restrict__ wprojb,
                                                  u16* __restrict__ tpb,
                                                  u16* __restrict__ ttwb,
                                                  u16* __restrict__ tt1wb) {
    int bx = blockIdx.x, tid = threadIdx.x;
    const float* s;
    u16* d8;
    if (bx < 3120) {
        size_t idx8 = ((size_t)bx * 256 + tid) * 8;
        int c = idx8 % DIM_;
        int n = (idx8 / DIM_) % NTOK_;
        int b = idx8 / ((size_t)DIM_ * NTOK_);
        s = (n < NT_) ? tp + ((size_t)b * NT_ + n) * DIM_ + c
                      : x + ((size_t)b * PIX_ + (n - NT_)) * DIM_ + c;
        d8 = xcb + idx8;
    } else {
        int i = (bx - 3120) * 256 + tid;
        const float* src;
        u16* dst;
        int li;
        if (i < 221184)      { src = qkv_w;  dst = wqkvb;  li = i; }
        else if (i < 294912) { src = proj_w; dst = wprojb; li = i - 221184; }
        else if (i < 307200) { src = tp;     dst = tpb;    li = i - 294912; }
        else if (i < 405504) { src = tt_w;   dst = ttwb;   li = i - 307200; }
        else if (i < 503808) { src = tt1_w;  dst = tt1wb;  li = i - 405504; }
        else return;
        s = src + (size_t)li * 8;
        d8 = dst + (size_t)li * 8;
    }
    float4 a = *(const float4*)s;
    float4 d = *(const float4*)(s + 4);
    u16x8 r;
    r[0] = f2b(a.x); r[1] = f2b(a.y); r[2] = f2b(a.z); r[3] = f2b(a.w);
    r[4] = f2b(d.x); r[5] = f2b(d.y); r[6] = f2b(d.z); r[7] = f2b(d.w);
    *(u16x8*)d8 = r;
}

// =================== generic bf16 MFMA GEMM: C = A(MxK) @ W(NxK)^T ===================
// Staging via global_load_lds (16B/lane, linear LDS [128][32]).
// MODE 0: QKV scatter -> q,k,v bf16 row-major (B,H,1152,96)
// MODE 1: scores -> raw fp32 NT-store (guarded) + per-(row,jtile) softmax partials (o1)
// MODE 2: proj(+bias) -> split tp_out(o1)/x_out(o0, NT) fp32
// MODE 3: plain bf16 out (+bias) to oq, stride ldo
// MODE 4: plain fp32 out (+bias) to o0, stride ldo
template <int MODE>
__global__ __launch_bounds__(256) void gemm_bf16(
    const u16* __restrict__ A, const u16* __restrict__ Bw,
    int lda, int ldb, int K, size_t strA, size_t strB,
    const float* __restrict__ bias,
    float* __restrict__ o0, float* __restrict__ o1,
    u16* __restrict__ oq, u16* __restrict__ ok, u16* __restrict__ ov,
    int ldo) {
    __shared__ u16 As[128 * 32];
    __shared__ u16 Bs[128 * 32];
    __shared__ float redm[128][2];
    __shared__ float reds[128][2];
    const int tid = threadIdx.x;
    const int bm = blockIdx.x, bn = blockIdx.y, z = blockIdx.z;
    const u16* Ab = A + strA * z;
    const u16* Bb = Bw + strB * z;
    const int lane = tid & 63, wid = tid >> 6;
    const int ln = lane & 15, hi = lane >> 4;
    const int wr = wid >> 1, wc = wid & 1;
    const int lrow = lane >> 2;          // 0..15 within 16-row group
    const int lcol = (lane & 3) * 8;     // u16 col offset within 32
    f32x4 acc[4][4] = {};
    for (int kt = 0; kt < K; kt += 32) {
        __syncthreads();
#pragma unroll
        for (int t = 0; t < 2; ++t) {
            int rowbase = t * 64 + wid * 16;
            const u16* ga = Ab + (size_t)(bm * 128 + rowbase + lrow) * lda + kt + lcol;
            const u16* gb = Bb + (size_t)(bn * 128 + rowbase + lrow) * ldb + kt + lcol;
            gload_lds16(ga, &As[rowbase * 32]);
            gload_lds16(gb, &Bs[rowbase * 32]);
        }
        __syncthreads();
        bf16x8 af[4], bfr[4];
#pragma unroll
        for (int m = 0; m < 4; ++m)
            af[m] = *(const bf16x8*)&As[(wr * 64 + m * 16 + ln) * 32 + hi * 8];
#pragma unroll
        for (int n = 0; n < 4; ++n)
            bfr[n] = *(const bf16x8*)&Bs[(wc * 64 + n * 16 + ln) * 32 + hi * 8];
#pragma unroll
        for (int m = 0; m < 4; ++m)
#pragma unroll
            for (int n = 0; n < 4; ++n)
                acc[m][n] = __builtin_amdgcn_mfma_f32_16x16x32_bf16(af[m], bfr[n], acc[m][n], 0, 0, 0);
    }
#pragma unroll
    for (int m = 0; m < 4; ++m) {
#pragma unroll
        for (int n = 0; n < 4; ++n) {
#pragma unroll
            for (int j = 0; j < 4; ++j) {
                int gm = bm * 128 + wr * 64 + m * 16 + hi * 4 + j;
                int gn = bn * 128 + wc * 64 + n * 16 + ln;
                float v = acc[m][n][j];
                if (MODE == 0) {
                    int b = gm / NTOK_, nn = gm - b * NTOK_;
                    int s = gn / DIM_, rem = gn - s * DIM_;
                    int h = rem / HD_, d = rem - h * HD_;
                    u16 hv = f2b(v);
                    u16* dst = (s == 0) ? oq : (s == 1) ? ok : ov;
                    dst[(((size_t)b * HEADS_ + h) * NPAD_ + nn) * HD_ + d] = hv;
                } else if (MODE == 1) {
                    if (gm < NTOK_ && gn < NTOK_)
                        __builtin_nontemporal_store(v, &o0[((size_t)z * NTOK_ + gm) * NTOK_ + gn]);
                } else if (MODE == 2) {
                    v += bias[gn];
                    int b = gm / NTOK_, nn = gm - b * NTOK_;
                    if (nn < NT_) o1[((size_t)b * NT_ + nn) * DIM_ + gn] = v;
                    else          __builtin_nontemporal_store(v, &o0[((size_t)b * PIX_ + (nn - NT_)) * DIM_ + gn]);
                } else if (MODE == 3) {
                    oq[(size_t)gm * ldo + gn] = f2b(v + bias[gn]);
                } else {
                    o0[(size_t)gm * ldo + gn] = v + bias[gn];
                }
            }
        }
    }
    if (MODE == 1) {
#pragma unroll
        for (int m = 0; m < 4; ++m) {
#pragma unroll
            for (int j = 0; j < 4; ++j) {
                float v[4];
                float mx = -INFINITY;
#pragma unroll
                for (int n = 0; n < 4; ++n) {
                    int gn = bn * 128 + wc * 64 + n * 16 + ln;
                    v[n] = (gn < NTOK_) ? acc[m][n][j] * SCALE_SPA : -INFINITY;
                    mx = fmaxf(mx, v[n]);
                }
#pragma unroll
                for (int off = 1; off < 16; off <<= 1) mx = fmaxf(mx, __shfl_xor(mx, off));
                float s = 0.f;
                if (mx > -INFINITY) {
#pragma unroll
                    for (int n = 0; n < 4; ++n)
                        if (v[n] > -INFINITY) s += __expf(v[n] - mx);
                }
#pragma unroll
                for (int off = 1; off < 16; off <<= 1) s += __shfl_xor(s, off);
                if (ln == 0) {
                    int row = wr * 64 + m * 16 + hi * 4 + j;
                    redm[row][wc] = mx;
                    reds[row][wc] = s;
                }
            }
        }
        __syncthreads();
        if (tid < 128) {
            float m0 = redm[tid][0], m1 = redm[tid][1];
            float s0 = reds[tid][0], s1 = reds[tid][1];
            float M = fmaxf(m0, m1);
            float S = 0.f;
            if (m0 > -INFINITY) S += s0 * __expf(m0 - M);
            if (m1 > -INFINITY) S += s1 * __expf(m1 - M);
            float2* pp = (float2*)o1;
            pp[((size_t)z * 9 + bn) * NPAD_ + bm * 128 + tid] = make_float2(M, S);
        }
    }
}

// =================== v (B,H,1152,96) -> vT (B,H,96,1152) ===================
__global__ __launch_bounds__(256) void transpose_v(const u16* __restrict__ vb,
                                                   u16* __restrict__ vtb) {
    __shared__ u16 t[32][34];
    int bi = blockIdx.x, bj = blockIdx.y, z = blockIdx.z;
    const u16* ib = vb + (size_t)z * NPAD_ * HD_;
    u16* ob = vtb + (size_t)z * HD_ * NPAD_;
    int tid = threadIdx.x;
    int r = tid >> 3, c = (tid & 7) * 4;
    *(u16x4*)&t[r][c] = *(const u16x4*)(ib + (size_t)(bi * 32 + r) * HD_ + bj * 32 + c);
    __syncthreads();
    u16x4 o;
    o[0] = t[c + 0][r]; o[1] = t[c + 1][r]; o[2] = t[c + 2][r]; o[3] = t[c + 3][r];
    *(u16x4*)(ob + (size_t)(bj * 32 + r) * NPAD_ + bi * 32 + c) = o;
}

// =================== fused softmax + PV, 128 rows/block ===================
// NT load raw (stream-once), NT store attn (never re-read).
// 128-row tiles halve again per-z V re-reads from L2 and total barriers.
__global__ __launch_bounds__(256) void attn_pv5(const float* __restrict__ raw,
                                                const float2* __restrict__ part,
                                                const u16* __restrict__ vtb,
                                                float* __restrict__ attn,
                                                u16* __restrict__ acat) {
    __shared__ u16 Ps[128][136];
    __shared__ float sm[128], si[128];
    const int tid = threadIdx.x;
    const int bi = blockIdx.x, z = blockIdx.y;
    if (tid < 128) {
        int grow = bi * 128 + tid;
        float M = -INFINITY;
        float mj[9], sj[9];
#pragma unroll
        for (int jt = 0; jt < 9; ++jt) {
            float2 p = part[((size_t)z * 9 + jt) * NPAD_ + grow];
            mj[jt] = p.x; sj[jt] = p.y;
            M = fmaxf(M, p.x);
        }
        float S = 0.f;
#pragma unroll
        for (int jt = 0; jt < 9; ++jt)
            if (mj[jt] > -INFINITY) S += sj[jt] * __expf(mj[jt] - M);
        sm[tid] = M;
        si[tid] = 1.f / S;
    }
    __syncthreads();
    const int lane = tid & 63, wid = tid >> 6;
    const int ln = lane & 15, hi = lane >> 4;
    const int wr = wid >> 1, wc = wid & 1;
    const int r0 = tid >> 3, c8 = tid & 7;
    const u16* vbz = vtb + (size_t)z * HD_ * NPAD_;
    const float* rawz = raw + (size_t)z * NTOK_ * NTOK_;
    float* attnz = attn + (size_t)z * NTOK_ * NTOK_;
    int rows[4];
    bool vr[4];
    float mr[4], ir[4];
#pragma unroll
    for (int p = 0; p < 4; ++p) {
        int rr = p * 32 + r0;
        rows[p] = bi * 128 + rr;
        vr[p] = rows[p] < NTOK_;
        mr[p] = sm[rr];
        ir[p] = si[rr];
    }
    f32x4 oacc[4][3] = {};
    for (int c0 = 0; c0 < 1056; c0 += 128) {
        const int nsub = (c0 == 1024) ? 1 : 4;
#pragma unroll 4
        for (int s = 0; s < nsub; ++s) {
            int cl = s * 32 + c8 * 4;
            int col = c0 + cl;
#pragma unroll
            for (int p = 0; p < 4; ++p) {
                int rr = p * 32 + r0;
                bool okc = vr[p] && (col < NTOK_);
                u16x4 pb = {0, 0, 0, 0};
                if (okc) {
                    const float* rp = rawz + (size_t)rows[p] * NTOK_ + col;
                    f32x4 v = __builtin_nontemporal_load((const f32x4*)rp);
                    f32x4 pr;
                    pr[0] = __expf(v[0] * SCALE_SPA - mr[p]) * ir[p];
                    pr[1] = __expf(v[1] * SCALE_SPA - mr[p]) * ir[p];
                    pr[2] = __expf(v[2] * SCALE_SPA - mr[p]) * ir[p];
                    pr[3] = __expf(v[3] * SCALE_SPA - mr[p]) * ir[p];
                    __builtin_nontemporal_store(pr, (f32x4*)(attnz + (size_t)rows[p] * NTOK_ + col));
                    pb[0] = f2b_fast(pr[0]); pb[1] = f2b_fast(pr[1]);
                    pb[2] = f2b_fast(pr[2]); pb[3] = f2b_fast(pr[3]);
                }
                *(u16x4*)&Ps[rr][cl] = pb;
            }
        }
        __syncthreads();
#pragma unroll 4
        for (int ktl = 0; ktl < nsub; ++ktl) {
            bf16x8 af[4];
#pragma unroll
            for (int m = 0; m < 4; ++m)
                af[m] = *(const bf16x8*)&Ps[wr * 64 + m * 16 + ln][ktl * 32 + hi * 8];
#pragma unroll
            for (int n = 0; n < 3; ++n) {
                bf16x8 bv = *(const bf16x8*)(vbz + (size_t)(wc * 48 + n * 16 + ln) * NPAD_
                                             + c0 + ktl * 32 + hi * 8);
#pragma unroll
                for (int m = 0; m < 4; ++m)
                    oacc[m][n] = __builtin_amdgcn_mfma_f32_16x16x32_bf16(af[m], bv, oacc[m][n], 0, 0, 0);
            }
        }
        __syncthreads();
    }
    const int b = z >> 3, h = z & 7;
#pragma unroll
    for (int m = 0; m < 4; ++m)
#pragma unroll
        for (int n = 0; n < 3; ++n)
#pragma unroll
            for (int j = 0; j < 4; ++j) {
                int gi = bi * 128 + wr * 64 + m * 16 + hi * 4 + j;
                if (gi < NTOK_) {
                    int gd = wc * 48 + n * 16 + ln;
                    acat[((size_t)b * NTOK_ + gi) * DIM_ + h * HD_ + gd] = f2b(oacc[m][n][j]);
                }
            }
}

// =================== windowed channel scores (bf16 chanp) ===================
__global__ __launch_bounds__(256) void chan_scores(const u16* __restrict__ chanpb,
                                                   const float* __restrict__ x,
                                                   float* __restrict__ rawchan_ws,
                                                   float* __restrict__ out_raw) {
    int blk = blockIdx.x;  // b*16 + w
    int b = blk / 16, w = blk % 16;
    int cy = blockIdx.y;   // 6 chunks of 8 cc
    int nh = w / 4, nw = w % 4;
    __shared__ float qp[16][65];
    __shared__ float xs[64][17];
    int tid = threadIdx.x;
    for (int l = tid; l < 16 * 64; l += 256) {
        int t = l / 64, d = l % 64;
        int wh = d / 8, ww = d % 8;
        int pix = (nh * 8 + wh) * 32 + nw * 8 + ww;
        qp[t][d] = b2f(chanpb[((size_t)b * NT_ + t) * PIX_ + pix]);
    }
    __syncthreads();
    int t = tid % 16, cl = tid / 16;
    for (int cc = cy * 8; cc < cy * 8 + 8; ++cc) {
        for (int l = tid; l < 64 * 16; l += 256) {
            int d = l / 16, c2 = l % 16;
            int wh = d / 8, ww = d % 8;
            int pix = (nh * 8 + wh) * 32 + nw * 8 + ww;
            xs[d][c2] = x[((size_t)b * PIX_ + pix) * DIM_ + cc * 16 + c2];
        }
        __syncthreads();
        float acc = 0.f;
#pragma unroll
        for (int d = 0; d < 64; ++d) acc += qp[t][d] * xs[d][cl];
        int c = cc * 16 + cl;
        rawchan_ws[(((size_t)b * 16 + w) * NT_ + t) * DIM_ + c] = acc;
        out_raw[(((size_t)b * NT_ + t) * DIM_ + c) * 16 + w] = acc;
        __syncthreads();
    }
}

// =================== chan softmax over c (768), scattered write ===================
__global__ __launch_bounds__(256) void chan_softmax(const float* __restrict__ rawchan_ws,
                                                    float* __restrict__ out_attn) {
    int row = blockIdx.x;  // (b*16+w)*16 + t
    int b = row / 256;
    int w = (row / 16) % 16;
    int t = row % 16;
    const float* rp = rawchan_ws + (size_t)row * DIM_;
    int tid = threadIdx.x;
    float vals[3];
    float m = -INFINITY;
#pragma unroll
    for (int i = 0; i < 3; ++i) {
        vals[i] = rp[tid + i * 256] * 0.125f;
        m = fmaxf(m, vals[i]);
    }
    __shared__ float redm[4], reds[4];
    for (int off = 32; off; off >>= 1) m = fmaxf(m, __shfl_xor(m, off));
    if ((tid & 63) == 0) redm[tid >> 6] = m;
    __syncthreads();
    m = fmaxf(fmaxf(redm[0], redm[1]), fmaxf(redm[2], redm[3]));
    float s = 0.f;
#pragma unroll
    for (int i = 0; i < 3; ++i) { vals[i] = __expf(vals[i] - m); s += vals[i]; }
    for (int off = 32; off; off >>= 1) s += __shfl_xor(s, off);
    if ((tid & 63) == 0) reds[tid >> 6] = s;
    __syncthreads();
    s = reds[0] + reds[1] + reds[2] + reds[3];
    float inv = 1.f / s;
#pragma unroll
    for (int i = 0; i < 3; ++i) {
        int c = tid + i * 256;
        out_attn[(((size_t)b * NT_ + t) * DIM_ + c) * 16 + w] = vals[i] * inv;
    }
}

// =================== quaternion double conv (per (b,t) block) ===================
__global__ __launch_bounds__(256) void quat_conv(const float* __restrict__ tp,
                                                 const float* __restrict__ tpo,
                                                 const float* __restrict__ chp,
                                                 const float* __restrict__ qf_r, const float* __restrict__ qf_i,
                                                 const float* __restrict__ qf_j, const float* __restrict__ qf_k,
                                                 const float* __restrict__ qf_b,
                                                 const float* __restrict__ dqf_r, const float* __restrict__ dqf_i,
                                                 const float* __restrict__ dqf_j, const float* __restrict__ dqf_k,
                                                 const float* __restrict__ dqf_b,
                                                 float* __restrict__ fe2_out,
                                                 float* __restrict__ partials) {
    int blk = blockIdx.x;  // b*16 + t
    int b = blk / NT_, t = blk % NT_;
    __shared__ float w1[8][4][3];
    __shared__ float w2[8][4][3];
    __shared__ float w2c[4][8][3];
    __shared__ float qs[4][770];
    __shared__ float fs[8][770];
    __shared__ float wsum[4][4], wsq[4][4];
    int tid = threadIdx.x;
    if (tid < 96) {
        int o = tid / 12, rest = tid % 12, ic = rest / 3, tap = rest % 3;
        int g = o / 2, oo = o % 2;
        const int   cidx[4][4] = {{0, 1, 2, 3}, {1, 0, 3, 2}, {2, 3, 0, 1}, {3, 2, 1, 0}};
        const float csgn[4][4] = {{1, -1, -1, -1}, {1, 1, -1, 1}, {1, 1, 1, -1}, {1, -1, 1, 1}};
        const float* s1[4] = {qf_r, qf_i, qf_j, qf_k};
        const float* s2[4] = {dqf_r, dqf_i, dqf_j, dqf_k};
        w1[o][ic][tap] = csgn[g][ic] * s1[cidx[g][ic]][oo * 3 + tap];
        w2[o][ic][tap] = csgn[g][ic] * s2[cidx[g][ic]][oo * 3 + tap];
    }
    for (int l = tid; l < DIM_; l += 256) {
        size_t base = ((size_t)b * NT_ + t) * DIM_ + l;
        qs[0][1 + l] = 0.f;
        qs[1][1 + l] = tp[base];
        qs[2][1 + l] = tpo[base];
        qs[3][1 + l] = chp[base];
    }
    if (tid < 4) { qs[tid][0] = 0.f; qs[tid][769] = 0.f; }
    if (tid < 8) { fs[tid][0] = 0.f; fs[tid][769] = 0.f; }
    __syncthreads();
    if (tid < 96) {
        int o2 = tid / 24, rest = tid % 24, i2 = rest / 3, tap = rest % 3;
        w2c[o2][i2][tap] = w2[i2][o2][2 - tap];
    }
    for (int l = tid; l < DIM_; l += 256) {
#pragma unroll
        for (int o = 0; o < 8; ++o) {
            float a = qf_b[o];
#pragma unroll
            for (int ic = 0; ic < 4; ++ic)
#pragma unroll
                for (int tap = 0; tap < 3; ++tap) a += w1[o][ic][tap] * qs[ic][l + tap];
            fs[o][1 + l] = a;
        }
    }
    __syncthreads();
    float lsum[4] = {}, lsq[4] = {};
    for (int l = tid; l < DIM_; l += 256) {
#pragma unroll
        for (int o2 = 0; o2 < 4; ++o2) {
            float a = dqf_b[o2];
#pragma unroll
            for (int i2 = 0; i2 < 8; ++i2)
#pragma unroll
                for (int tap = 0; tap < 3; ++tap) a += w2c[o2][i2][tap] * fs[i2][l + tap];
            fe2_out[((size_t)blk * 4 + o2) * DIM_ + l] = a;
            lsum[o2] += a;
            lsq[o2] += a * a;
        }
    }
    int wid = tid >> 6;
#pragma unroll
    for (int o2 = 0; o2 < 4; ++o2) {
        float s = lsum[o2], q = lsq[o2];
        for (int off = 32; off; off >>= 1) { s += __shfl_xor(s, off); q += __shfl_xor(q, off); }
        if ((tid & 63) == 0) { wsum[wid][o2] = s; wsq[wid][o2] = q; }
    }
    __syncthreads();
    if (tid < 4) {
        float s = wsum[0][tid] + wsum[1][tid] + wsum[2][tid] + wsum[3][tid];
        float q = wsq[0][tid] + wsq[1][tid] + wsq[2][tid] + wsq[3][tid];
        partials[(size_t)blk * 8 + tid * 2 + 0] = s;
        partials[(size_t)blk * 8 + tid * 2 + 1] = q;
    }
}

// =================== BN + exact GELU + channel mix ===================
__global__ __launch_bounds__(256) void bn_gelu_out(const float* __restrict__ fe2,
                                                   const float* __restrict__ partials,
                                                   const float* __restrict__ bn_g,
                                                   const float* __restrict__ bn_b,
                                                   const float* __restrict__ qfto,
                                                   float* __restrict__ out5) {
    int blk = blockIdx.x;  // b*16 + t
    int b = blk / NT_;
    int tid = threadIdx.x;
    float mean[4], rstd[4], gam[4], bet[4], qw[4];
#pragma unroll
    for (int kk = 0; kk < 4; ++kk) {
        float s = 0.f, q = 0.f;
        for (int t2 = 0; t2 < 16; ++t2) {
            const float* p = partials + ((size_t)(b * NT_ + t2) * 8 + kk * 2);
            s += p[0];
            q += p[1];
        }
        float mu = s * (1.f / 12288.f);
        float var = q * (1.f / 12288.f) - mu * mu;
        mean[kk] = mu;
        rstd[kk] = rsqrtf(var + 1e-5f);
        gam[kk] = bn_g[kk];
        bet[kk] = bn_b[kk];
        qw[kk] = qfto[kk];
    }
    for (int l = tid; l < DIM_; l += 256) {
        float acc = 0.f;
#pragma unroll
        for (int kk = 0; kk < 4; ++kk) {
            float v = fe2[((size_t)blk * 4 + kk) * DIM_ + l];
            float nrm = (v - mean[kk]) * rstd[kk] * gam[kk] + bet[kk];
            float ge = 0.5f * nrm * (1.f + erff(nrm * 0.7071067811865475f));
            acc += ge * qw[kk];
        }
        out5[(size_t)blk * DIM_ + l] = acc;
    }
}

// =================== launch ===================
extern "C" void kernel_launch(void* const* d_in, const int* in_sizes, int n_in,
                              void* d_out, int out_size, void* d_ws, size_t ws_size,
                              hipStream_t stream) {
    const float* x      = (const float*)d_in[0];
    const float* tp     = (const float*)d_in[1];
    const float* qkv_w  = (const float*)d_in[2];
    const float* proj_w = (const float*)d_in[3];
    const float* proj_b = (const float*)d_in[4];
    const float* tt_w   = (const float*)d_in[5];
    const float* tt_b   = (const float*)d_in[6];
    const float* tt1_w  = (const float*)d_in[7];
    const float* tt1_b  = (const float*)d_in[8];
    const float* qf_r   = (const float*)d_in[9];
    const float* qf_i   = (const float*)d_in[10];
    const float* qf_j   = (const float*)d_in[11];
    const float* qf_k   = (const float*)d_in[12];
    const float* qf_b   = (const float*)d_in[13];
    const float* dqf_r  = (const float*)d_in[14];
    const float* dqf_i  = (const float*)d_in[15];
    const float* dqf_j  = (const float*)d_in[16];
    const float* dqf_k  = (const float*)d_in[17];
    const float* dqf_b  = (const float*)d_in[18];
    const float* bn_g   = (const float*)d_in[19];
    const float* bn_b   = (const float*)d_in[20];
    const float* qfto   = (const float*)d_in[21];
    float* out = (float*)d_out;
    char* wsb = (char*)d_ws;

    u16* xcb    = (u16*)(wsb + WSO_XCB);
    u16* wqkvb  = (u16*)(wsb + WSO_WQKV);
    u16* wprojb = (u16*)(wsb + WSO_WPROJ);
    u16* qb     = (u16*)(wsb + WSO_QB);
    u16* kb     = (u16*)(wsb + WSO_KB);
    u16* vb     = (u16*)(wsb + WSO_VB);
    u16* vtb    = (u16*)(wsb + WSO_VTB);
    u16* acatb  = (u16*)(wsb + WSO_ACATB);
    u16* tpb    = (u16*)(wsb + WSO_TPB);
    u16* ttwb   = (u16*)(wsb + WSO_TTWB);
    u16* tt1wb  = (u16*)(wsb + WSO_TT1WB);
    u16* chanpb = (u16*)(wsb + WSO_CHANPB);
    float* partb = (float*)(wsb + WSO_PART);
    float* f32r = (float*)(wsb + WSO_F32);
    float* tpout   = f32r + FO_TPOUT;
    float* rawchan = f32r + FO_RAWCHAN;
    float* chpf    = f32r + FO_CHP;
    float* fe2     = f32r + FO_FE2;
    float* stats   = f32r + FO_STATS;

    // all casts (one launch)
    cast_fused<<<5088, 256, 0, stream>>>(tp, x, qkv_w, proj_w, tt_w, tt1_w,
                                         xcb, wqkvb, wprojb, tpb, ttwb, tt1wb);

    // QKV: (8320x768) @ (2304x768)^T -> q,k,v bf16 row-major
    gemm_bf16<0><<<dim3(65, 18, 1), 256, 0, stream>>>(xcb, wqkvb, 768, 768, 768, 0, 0,
                                                      nullptr, nullptr, nullptr, qb, kb, vb, 0);
    // v -> vT
    transpose_v<<<dim3(36, 3, 64), 256, 0, stream>>>(vb, vtb);
    // scores -> raw (output 2, NT) + softmax partials
    gemm_bf16<1><<<dim3(9, 9, 64), 256, 0, stream>>>(qb, kb, 96, 96, 96,
                                                     (size_t)NPAD_ * HD_, (size_t)NPAD_ * HD_,
                                                     nullptr, out + OUT_RAW, partb,
                                                     nullptr, nullptr, nullptr, 0);
    // fused softmax (output 3, NT) + PV -> acat bf16 (128 rows/block)
    attn_pv5<<<dim3(9, 64), 256, 0, stream>>>(out + OUT_RAW, (const float2*)partb,
                                              vtb, out + OUT_ATTN, acatb);
    // proj -> x_out (output 1, NT) + tp_out
    gemm_bf16<2><<<dim3(65, 6, 1), 256, 0, stream>>>(acatb, wprojb, 768, 768, 768, 0, 0,
                                                     proj_b, out + OUT_XOUT, tpout,
                                                     nullptr, nullptr, nullptr, 0);
    // chanp = tp @ tt_w^T + tt_b  (bf16 out)
    gemm_bf16<3><<<dim3(1, 8, 1), 256, 0, stream>>>(tpb, ttwb, 768, 768, 768, 0, 0,
                                                    tt_b, nullptr, nullptr, chanpb, nullptr, nullptr, 1024);
    // windowed channel scores (output 4)
    chan_scores<<<dim3(128, 6), 256, 0, stream>>>(chanpb, x, rawchan, out + OUT_RAWCH);
    // chan softmax (output 5)
    chan_softmax<<<2048, 256, 0, stream>>>(rawchan, out + OUT_ATTNCH);
    // ch_prompts = chanp @ tt1_w^T + tt1_b  (fp32 out)
    gemm_bf16<4><<<dim3(1, 6, 1), 256, 0, stream>>>(chanpb, tt1wb, 1024, 1024, 1024, 0, 0,
                                                    tt1_b, chpf, nullptr, nullptr, nullptr, nullptr, 768);
    // quaternion conv + BN + GELU + mix (output 6)
    quat_conv<<<128, 256, 0, stream>>>(tp, tpout, chpf,
                                       qf_r, qf_i, qf_j, qf_k, qf_b,
                                       dqf_r, dqf_i, dqf_j, dqf_k, dqf_b,
                                       fe2, stats);
    bn_gelu_out<<<128, 256, 0, stream>>>(fe2, stats, bn_g, bn_b, qfto, out + OUT_QOUT);
}

// Round 16
// 496.984 us; speedup vs baseline: 1.0193x; 1.0193x over previous
//
#include <hip/hip_runtime.h>
#include <hip/hip_bf16.h>
#include <math.h>

typedef unsigned short u16;
typedef __attribute__((ext_vector_type(8))) short  bf16x8;
typedef __attribute__((ext_vector_type(4))) float  f32x4;
typedef __attribute__((ext_vector_type(8))) u16    u16x8;
typedef __attribute__((ext_vector_type(4))) u16    u16x4;

// ---------------- problem constants ----------------
#define B_      8
#define NT_     16
#define DIM_    768
#define HEADS_  8
#define HD_     96
#define PIX_    1024
#define NTOK_   1040
#define NPAD_   1152

// ---------------- workspace layout (byte offsets) ----------------
#define WSO_XCB     0ull
#define WSO_WQKV    12779520ull
#define WSO_WPROJ   16318464ull
#define WSO_QB      17498112ull
#define WSO_KB      31653888ull
#define WSO_VB      45809664ull
#define WSO_VTB     59965440ull
#define WSO_ACATB   74121216ull
#define WSO_TPB     86900736ull
#define WSO_TTWB    87097344ull
#define WSO_TT1WB   88670208ull
#define WSO_CHANPB  90243072ull
#define WSO_PART    90505216ull    // (64,9,1152) float2
#define WSO_F32     95813632ull
// fp32 region offsets (floats)
#define FO_TPOUT    0ull           // 98,304
#define FO_RAWCHAN  98304ull       // 1,572,864
#define FO_CHP      1671168ull     // 98,304
#define FO_FE2      1769472ull     // 393,216
#define FO_STATS    2162688ull     // 1024

// ---------------- output layout (float offsets) ----------------
#define OUT_XOUT   0ull
#define OUT_RAW    6291456ull
#define OUT_ATTN   75513856ull
#define OUT_RAWCH  144736256ull
#define OUT_ATTNCH 146309120ull
#define OUT_QOUT   147881984ull

#define SCALE_SPA 0.1020620726159658f   // 96^-0.5

__device__ __forceinline__ u16 f2b(float f) {
    union { float f; unsigned u; } x; x.f = f;
    unsigned r = x.u + 0x7FFFu + ((x.u >> 16) & 1u);
    return (u16)(r >> 16);
}
__device__ __forceinline__ u16 f2b_fast(float f) {
    __hip_bfloat16 h = __float2bfloat16(f);
    return __builtin_bit_cast(u16, h);
}
__device__ __forceinline__ float b2f(u16 h) {
    union { unsigned u; float f; } x; x.u = ((unsigned)h) << 16;
    return x.f;
}

// async global->LDS, 16B per lane, wave-uniform LDS base
__device__ __forceinline__ void gload_lds16(const u16* gsrc, u16* ldst) {
    __builtin_amdgcn_global_load_lds((const __attribute__((address_space(1))) void*)gsrc,
                                     (__attribute__((address_space(3))) void*)ldst,
                                     16, 0, 0);
}

// =================== all casts in one launch (same resource class) ===================
__global__ __launch_bounds__(256) void cast_fused(const float* __restrict__ tp,
                                                  const float* __restrict__ x,
                                                  const float* __restrict__ qkv_w,
                                                  const float* __restrict__ proj_w,
                                                  const float* __restrict__ tt_w,
                                                  const float* __restrict__ tt1_w,
                                                  u16* __restrict__ xcb,
                                                  u16* __restrict__ wqkvb,
                                                  u16* __restrict__ wprojb,
                                                  u16* __restrict__ tpb,
                                                  u16* __restrict__ ttwb,
                                                  u16* __restrict__ tt1wb) {
    int bx = blockIdx.x, tid = threadIdx.x;
    const float* s;
    u16* d8;
    if (bx < 3120) {
        size_t idx8 = ((size_t)bx * 256 + tid) * 8;
        int c = idx8 % DIM_;
        int n = (idx8 / DIM_) % NTOK_;
        int b = idx8 / ((size_t)DIM_ * NTOK_);
        s = (n < NT_) ? tp + ((size_t)b * NT_ + n) * DIM_ + c
                      : x + ((size_t)b * PIX_ + (n - NT_)) * DIM_ + c;
        d8 = xcb + idx8;
    } else {
        int i = (bx - 3120) * 256 + tid;
        const float* src;
        u16* dst;
        int li;
        if (i < 221184)      { src = qkv_w;  dst = wqkvb;  li = i; }
        else if (i < 294912) { src = proj_w; dst = wprojb; li = i - 221184; }
        else if (i < 307200) { src = tp;     dst = tpb;    li = i - 294912; }
        else if (i < 405504) { src = tt_w;   dst = ttwb;   li = i - 307200; }
        else if (i < 503808) { src = tt1_w;  dst = tt1wb;  li = i - 405504; }
        else return;
        s = src + (size_t)li * 8;
        d8 = dst + (size_t)li * 8;
    }
    float4 a = *(const float4*)s;
    float4 d = *(const float4*)(s + 4);
    u16x8 r;
    r[0] = f2b(a.x); r[1] = f2b(a.y); r[2] = f2b(a.z); r[3] = f2b(a.w);
    r[4] = f2b(d.x); r[5] = f2b(d.y); r[6] = f2b(d.z); r[7] = f2b(d.w);
    *(u16x8*)d8 = r;
}

// =================== generic bf16 MFMA GEMM: C = A(MxK) @ W(NxK)^T ===================
// Staging via global_load_lds (16B/lane, linear LDS [128][32]).
// MODE 0: QKV scatter -> q,k,v bf16 row-major (B,H,1152,96)
// MODE 1: scores -> raw fp32 NT-store (guarded) + per-(row,jtile) softmax partials (o1)
// MODE 2: proj(+bias) -> split tp_out(o1)/x_out(o0, NT) fp32
// MODE 3: plain bf16 out (+bias) to oq, stride ldo
// MODE 4: plain fp32 out (+bias) to o0, stride ldo
template <int MODE>
__global__ __launch_bounds__(256) void gemm_bf16(
    const u16* __restrict__ A, const u16* __restrict__ Bw,
    int lda, int ldb, int K, size_t strA, size_t strB,
    const float* __restrict__ bias,
    float* __restrict__ o0, float* __restrict__ o1,
    u16* __restrict__ oq, u16* __restrict__ ok, u16* __restrict__ ov,
    int ldo) {
    __shared__ u16 As[128 * 32];
    __shared__ u16 Bs[128 * 32];
    __shared__ float redm[128][2];
    __shared__ float reds[128][2];
    const int tid = threadIdx.x;
    const int bm = blockIdx.x, bn = blockIdx.y, z = blockIdx.z;
    const u16* Ab = A + strA * z;
    const u16* Bb = Bw + strB * z;
    const int lane = tid & 63, wid = tid >> 6;
    const int ln = lane & 15, hi = lane >> 4;
    const int wr = wid >> 1, wc = wid & 1;
    const int lrow = lane >> 2;          // 0..15 within 16-row group
    const int lcol = (lane & 3) * 8;     // u16 col offset within 32
    f32x4 acc[4][4] = {};
    for (int kt = 0; kt < K; kt += 32) {
        __syncthreads();
#pragma unroll
        for (int t = 0; t < 2; ++t) {
            int rowbase = t * 64 + wid * 16;
            const u16* ga = Ab + (size_t)(bm * 128 + rowbase + lrow) * lda + kt + lcol;
            const u16* gb = Bb + (size_t)(bn * 128 + rowbase + lrow) * ldb + kt + lcol;
            gload_lds16(ga, &As[rowbase * 32]);
            gload_lds16(gb, &Bs[rowbase * 32]);
        }
        __syncthreads();
        bf16x8 af[4], bfr[4];
#pragma unroll
        for (int m = 0; m < 4; ++m)
            af[m] = *(const bf16x8*)&As[(wr * 64 + m * 16 + ln) * 32 + hi * 8];
#pragma unroll
        for (int n = 0; n < 4; ++n)
            bfr[n] = *(const bf16x8*)&Bs[(wc * 64 + n * 16 + ln) * 32 + hi * 8];
#pragma unroll
        for (int m = 0; m < 4; ++m)
#pragma unroll
            for (int n = 0; n < 4; ++n)
                acc[m][n] = __builtin_amdgcn_mfma_f32_16x16x32_bf16(af[m], bfr[n], acc[m][n], 0, 0, 0);
    }
#pragma unroll
    for (int m = 0; m < 4; ++m) {
#pragma unroll
        for (int n = 0; n < 4; ++n) {
#pragma unroll
            for (int j = 0; j < 4; ++j) {
                int gm = bm * 128 + wr * 64 + m * 16 + hi * 4 + j;
                int gn = bn * 128 + wc * 64 + n * 16 + ln;
                float v = acc[m][n][j];
                if (MODE == 0) {
                    int b = gm / NTOK_, nn = gm - b * NTOK_;
                    int s = gn / DIM_, rem = gn - s * DIM_;
                    int h = rem / HD_, d = rem - h * HD_;
                    u16 hv = f2b(v);
                    u16* dst = (s == 0) ? oq : (s == 1) ? ok : ov;
                    dst[(((size_t)b * HEADS_ + h) * NPAD_ + nn) * HD_ + d] = hv;
                } else if (MODE == 1) {
                    if (gm < NTOK_ && gn < NTOK_)
                        __builtin_nontemporal_store(v, &o0[((size_t)z * NTOK_ + gm) * NTOK_ + gn]);
                } else if (MODE == 2) {
                    v += bias[gn];
                    int b = gm / NTOK_, nn = gm - b * NTOK_;
                    if (nn < NT_) o1[((size_t)b * NT_ + nn) * DIM_ + gn] = v;
                    else          __builtin_nontemporal_store(v, &o0[((size_t)b * PIX_ + (nn - NT_)) * DIM_ + gn]);
                } else if (MODE == 3) {
                    oq[(size_t)gm * ldo + gn] = f2b(v + bias[gn]);
                } else {
                    o0[(size_t)gm * ldo + gn] = v + bias[gn];
                }
            }
        }
    }
    if (MODE == 1) {
#pragma unroll
        for (int m = 0; m < 4; ++m) {
#pragma unroll
            for (int j = 0; j < 4; ++j) {
                float v[4];
                float mx = -INFINITY;
#pragma unroll
                for (int n = 0; n < 4; ++n) {
                    int gn = bn * 128 + wc * 64 + n * 16 + ln;
                    v[n] = (gn < NTOK_) ? acc[m][n][j] * SCALE_SPA : -INFINITY;
                    mx = fmaxf(mx, v[n]);
                }
#pragma unroll
                for (int off = 1; off < 16; off <<= 1) mx = fmaxf(mx, __shfl_xor(mx, off));
                float s = 0.f;
                if (mx > -INFINITY) {
#pragma unroll
                    for (int n = 0; n < 4; ++n)
                        if (v[n] > -INFINITY) s += __expf(v[n] - mx);
                }
#pragma unroll
                for (int off = 1; off < 16; off <<= 1) s += __shfl_xor(s, off);
                if (ln == 0) {
                    int row = wr * 64 + m * 16 + hi * 4 + j;
                    redm[row][wc] = mx;
                    reds[row][wc] = s;
                }
            }
        }
        __syncthreads();
        if (tid < 128) {
            float m0 = redm[tid][0], m1 = redm[tid][1];
            float s0 = reds[tid][0], s1 = reds[tid][1];
            float M = fmaxf(m0, m1);
            float S = 0.f;
            if (m0 > -INFINITY) S += s0 * __expf(m0 - M);
            if (m1 > -INFINITY) S += s1 * __expf(m1 - M);
            float2* pp = (float2*)o1;
            pp[((size_t)z * 9 + bn) * NPAD_ + bm * 128 + tid] = make_float2(M, S);
        }
    }
}

// =================== v (B,H,1152,96) -> vT (B,H,96,1152) ===================
__global__ __launch_bounds__(256) void transpose_v(const u16* __restrict__ vb,
                                                   u16* __restrict__ vtb) {
    __shared__ u16 t[32][34];
    int bi = blockIdx.x, bj = blockIdx.y, z = blockIdx.z;
    const u16* ib = vb + (size_t)z * NPAD_ * HD_;
    u16* ob = vtb + (size_t)z * HD_ * NPAD_;
    int tid = threadIdx.x;
    int r = tid >> 3, c = (tid & 7) * 4;
    *(u16x4*)&t[r][c] = *(const u16x4*)(ib + (size_t)(bi * 32 + r) * HD_ + bj * 32 + c);
    __syncthreads();
    u16x4 o;
    o[0] = t[c + 0][r]; o[1] = t[c + 1][r]; o[2] = t[c + 2][r]; o[3] = t[c + 3][r];
    *(u16x4*)(ob + (size_t)(bj * 32 + r) * NPAD_ + bi * 32 + c) = o;
}

// =================== fused softmax + PV, 64 rows/block ===================
// NT load raw (stream-once), NT store attn (never re-read).
__global__ __launch_bounds__(256) void attn_pv4(const float* __restrict__ raw,
                                                const float2* __restrict__ part,
                                                const u16* __restrict__ vtb,
                                                float* __restrict__ attn,
                                                u16* __restrict__ acat) {
    __shared__ u16 Ps[64][136];
    __shared__ float sm[64], si[64];
    const int tid = threadIdx.x;
    const int bi = blockIdx.x, z = blockIdx.y;
    if (tid < 64) {
        int grow = bi * 64 + tid;
        float M = -INFINITY;
        float mj[9], sj[9];
#pragma unroll
        for (int jt = 0; jt < 9; ++jt) {
            float2 p = part[((size_t)z * 9 + jt) * NPAD_ + grow];
            mj[jt] = p.x; sj[jt] = p.y;
            M = fmaxf(M, p.x);
        }
        float S = 0.f;
#pragma unroll
        for (int jt = 0; jt < 9; ++jt)
            if (mj[jt] > -INFINITY) S += sj[jt] * __expf(mj[jt] - M);
        sm[tid] = M;
        si[tid] = 1.f / S;
    }
    __syncthreads();
    const int lane = tid & 63, wid = tid >> 6;
    const int ln = lane & 15, hi = lane >> 4;
    const int wr = wid >> 1, wc = wid & 1;
    const int r0 = tid >> 3, c8 = tid & 7;
    const u16* vbz = vtb + (size_t)z * HD_ * NPAD_;
    const float* rawz = raw + (size_t)z * NTOK_ * NTOK_;
    float* attnz = attn + (size_t)z * NTOK_ * NTOK_;
    int rows[2];
    bool vr[2];
    float mr[2], ir[2];
#pragma unroll
    for (int p = 0; p < 2; ++p) {
        int rr = p * 32 + r0;
        rows[p] = bi * 64 + rr;
        vr[p] = rows[p] < NTOK_;
        mr[p] = sm[rr];
        ir[p] = si[rr];
    }
    f32x4 oacc[2][3] = {};
    for (int c0 = 0; c0 < 1056; c0 += 128) {
        const int nsub = (c0 == 1024) ? 1 : 4;
#pragma unroll 4
        for (int s = 0; s < nsub; ++s) {
            int cl = s * 32 + c8 * 4;
            int col = c0 + cl;
#pragma unroll
            for (int p = 0; p < 2; ++p) {
                int rr = p * 32 + r0;
                bool okc = vr[p] && (col < NTOK_);
                u16x4 pb = {0, 0, 0, 0};
                if (okc) {
                    const float* rp = rawz + (size_t)rows[p] * NTOK_ + col;
                    f32x4 v = __builtin_nontemporal_load((const f32x4*)rp);
                    f32x4 pr;
                    pr[0] = __expf(v[0] * SCALE_SPA - mr[p]) * ir[p];
                    pr[1] = __expf(v[1] * SCALE_SPA - mr[p]) * ir[p];
                    pr[2] = __expf(v[2] * SCALE_SPA - mr[p]) * ir[p];
                    pr[3] = __expf(v[3] * SCALE_SPA - mr[p]) * ir[p];
                    __builtin_nontemporal_store(pr, (f32x4*)(attnz + (size_t)rows[p] * NTOK_ + col));
                    pb[0] = f2b_fast(pr[0]); pb[1] = f2b_fast(pr[1]);
                    pb[2] = f2b_fast(pr[2]); pb[3] = f2b_fast(pr[3]);
                }
                *(u16x4*)&Ps[rr][cl] = pb;
            }
        }
        __syncthreads();
#pragma unroll 4
        for (int ktl = 0; ktl < nsub; ++ktl) {
            bf16x8 af[2];
#pragma unroll
            for (int m = 0; m < 2; ++m)
                af[m] = *(const bf16x8*)&Ps[wr * 32 + m * 16 + ln][ktl * 32 + hi * 8];
#pragma unroll
            for (int n = 0; n < 3; ++n) {
                bf16x8 bv = *(const bf16x8*)(vbz + (size_t)(wc * 48 + n * 16 + ln) * NPAD_
                                             + c0 + ktl * 32 + hi * 8);
#pragma unroll
                for (int m = 0; m < 2; ++m)
                    oacc[m][n] = __builtin_amdgcn_mfma_f32_16x16x32_bf16(af[m], bv, oacc[m][n], 0, 0, 0);
            }
        }
        __syncthreads();
    }
    const int b = z >> 3, h = z & 7;
#pragma unroll
    for (int m = 0; m < 2; ++m)
#pragma unroll
        for (int n = 0; n < 3; ++n)
#pragma unroll
            for (int j = 0; j < 4; ++j) {
                int gi = bi * 64 + wr * 32 + m * 16 + hi * 4 + j;
                if (gi < NTOK_) {
                    int gd = wc * 48 + n * 16 + ln;
                    acat[((size_t)b * NTOK_ + gi) * DIM_ + h * HD_ + gd] = f2b(oacc[m][n][j]);
                }
            }
}

// =================== windowed channel scores (bf16 chanp) ===================
__global__ __launch_bounds__(256) void chan_scores(const u16* __restrict__ chanpb,
                                                   const float* __restrict__ x,
                                                   float* __restrict__ rawchan_ws,
                                                   float* __restrict__ out_raw) {
    int blk = blockIdx.x;  // b*16 + w
    int b = blk / 16, w = blk % 16;
    int cy = blockIdx.y;   // 6 chunks of 8 cc
    int nh = w / 4, nw = w % 4;
    __shared__ float qp[16][65];
    __shared__ float xs[64][17];
    int tid = threadIdx.x;
    for (int l = tid; l < 16 * 64; l += 256) {
        int t = l / 64, d = l % 64;
        int wh = d / 8, ww = d % 8;
        int pix = (nh * 8 + wh) * 32 + nw * 8 + ww;
        qp[t][d] = b2f(chanpb[((size_t)b * NT_ + t) * PIX_ + pix]);
    }
    __syncthreads();
    int t = tid % 16, cl = tid / 16;
    for (int cc = cy * 8; cc < cy * 8 + 8; ++cc) {
        for (int l = tid; l < 64 * 16; l += 256) {
            int d = l / 16, c2 = l % 16;
            int wh = d / 8, ww = d % 8;
            int pix = (nh * 8 + wh) * 32 + nw * 8 + ww;
            xs[d][c2] = x[((size_t)b * PIX_ + pix) * DIM_ + cc * 16 + c2];
        }
        __syncthreads();
        float acc = 0.f;
#pragma unroll
        for (int d = 0; d < 64; ++d) acc += qp[t][d] * xs[d][cl];
        int c = cc * 16 + cl;
        rawchan_ws[(((size_t)b * 16 + w) * NT_ + t) * DIM_ + c] = acc;
        out_raw[(((size_t)b * NT_ + t) * DIM_ + c) * 16 + w] = acc;
        __syncthreads();
    }
}

// =================== chan softmax over c (768), scattered write ===================
__global__ __launch_bounds__(256) void chan_softmax(const float* __restrict__ rawchan_ws,
                                                    float* __restrict__ out_attn) {
    int row = blockIdx.x;  // (b*16+w)*16 + t
    int b = row / 256;
    int w = (row / 16) % 16;
    int t = row % 16;
    const float* rp = rawchan_ws + (size_t)row * DIM_;
    int tid = threadIdx.x;
    float vals[3];
    float m = -INFINITY;
#pragma unroll
    for (int i = 0; i < 3; ++i) {
        vals[i] = rp[tid + i * 256] * 0.125f;
        m = fmaxf(m, vals[i]);
    }
    __shared__ float redm[4], reds[4];
    for (int off = 32; off; off >>= 1) m = fmaxf(m, __shfl_xor(m, off));
    if ((tid & 63) == 0) redm[tid >> 6] = m;
    __syncthreads();
    m = fmaxf(fmaxf(redm[0], redm[1]), fmaxf(redm[2], redm[3]));
    float s = 0.f;
#pragma unroll
    for (int i = 0; i < 3; ++i) { vals[i] = __expf(vals[i] - m); s += vals[i]; }
    for (int off = 32; off; off >>= 1) s += __shfl_xor(s, off);
    if ((tid & 63) == 0) reds[tid >> 6] = s;
    __syncthreads();
    s = reds[0] + reds[1] + reds[2] + reds[3];
    float inv = 1.f / s;
#pragma unroll
    for (int i = 0; i < 3; ++i) {
        int c = tid + i * 256;
        out_attn[(((size_t)b * NT_ + t) * DIM_ + c) * 16 + w] = vals[i] * inv;
    }
}

// =================== quaternion double conv (per (b,t) block) ===================
__global__ __launch_bounds__(256) void quat_conv(const float* __restrict__ tp,
                                                 const float* __restrict__ tpo,
                                                 const float* __restrict__ chp,
                                                 const float* __restrict__ qf_r, const float* __restrict__ qf_i,
                                                 const float* __restrict__ qf_j, const float* __restrict__ qf_k,
                                                 const float* __restrict__ qf_b,
                                                 const float* __restrict__ dqf_r, const float* __restrict__ dqf_i,
                                                 const float* __restrict__ dqf_j, const float* __restrict__ dqf_k,
                                                 const float* __restrict__ dqf_b,
                                                 float* __restrict__ fe2_out,
                                                 float* __restrict__ partials) {
    int blk = blockIdx.x;  // b*16 + t
    int b = blk / NT_, t = blk % NT_;
    __shared__ float w1[8][4][3];
    __shared__ float w2[8][4][3];
    __shared__ float w2c[4][8][3];
    __shared__ float qs[4][770];
    __shared__ float fs[8][770];
    __shared__ float wsum[4][4], wsq[4][4];
    int tid = threadIdx.x;
    if (tid < 96) {
        int o = tid / 12, rest = tid % 12, ic = rest / 3, tap = rest % 3;
        int g = o / 2, oo = o % 2;
        const int   cidx[4][4] = {{0, 1, 2, 3}, {1, 0, 3, 2}, {2, 3, 0, 1}, {3, 2, 1, 0}};
        const float csgn[4][4] = {{1, -1, -1, -1}, {1, 1, -1, 1}, {1, 1, 1, -1}, {1, -1, 1, 1}};
        const float* s1[4] = {qf_r, qf_i, qf_j, qf_k};
        const float* s2[4] = {dqf_r, dqf_i, dqf_j, dqf_k};
        w1[o][ic][tap] = csgn[g][ic] * s1[cidx[g][ic]][oo * 3 + tap];
        w2[o][ic][tap] = csgn[g][ic] * s2[cidx[g][ic]][oo * 3 + tap];
    }
    for (int l = tid; l < DIM_; l += 256) {
        size_t base = ((size_t)b * NT_ + t) * DIM_ + l;
        qs[0][1 + l] = 0.f;
        qs[1][1 + l] = tp[base];
        qs[2][1 + l] = tpo[base];
        qs[3][1 + l] = chp[base];
    }
    if (tid < 4) { qs[tid][0] = 0.f; qs[tid][769] = 0.f; }
    if (tid < 8) { fs[tid][0] = 0.f; fs[tid][769] = 0.f; }
    __syncthreads();
    if (tid < 96) {
        int o2 = tid / 24, rest = tid % 24, i2 = rest / 3, tap = rest % 3;
        w2c[o2][i2][tap] = w2[i2][o2][2 - tap];
    }
    for (int l = tid; l < DIM_; l += 256) {
#pragma unroll
        for (int o = 0; o < 8; ++o) {
            float a = qf_b[o];
#pragma unroll
            for (int ic = 0; ic < 4; ++ic)
#pragma unroll
                for (int tap = 0; tap < 3; ++tap) a += w1[o][ic][tap] * qs[ic][l + tap];
            fs[o][1 + l] = a;
        }
    }
    __syncthreads();
    float lsum[4] = {}, lsq[4] = {};
    for (int l = tid; l < DIM_; l += 256) {
#pragma unroll
        for (int o2 = 0; o2 < 4; ++o2) {
            float a = dqf_b[o2];
#pragma unroll
            for (int i2 = 0; i2 < 8; ++i2)
#pragma unroll
                for (int tap = 0; tap < 3; ++tap) a += w2c[o2][i2][tap] * fs[i2][l + tap];
            fe2_out[((size_t)blk * 4 + o2) * DIM_ + l] = a;
            lsum[o2] += a;
            lsq[o2] += a * a;
        }
    }
    int wid = tid >> 6;
#pragma unroll
    for (int o2 = 0; o2 < 4; ++o2) {
        float s = lsum[o2], q = lsq[o2];
        for (int off = 32; off; off >>= 1) { s += __shfl_xor(s, off); q += __shfl_xor(q, off); }
        if ((tid & 63) == 0) { wsum[wid][o2] = s; wsq[wid][o2] = q; }
    }
    __syncthreads();
    if (tid < 4) {
        float s = wsum[0][tid] + wsum[1][tid] + wsum[2][tid] + wsum[3][tid];
        float q = wsq[0][tid] + wsq[1][tid] + wsq[2][tid] + wsq[3][tid];
        partials[(size_t)blk * 8 + tid * 2 + 0] = s;
        partials[(size_t)blk * 8 + tid * 2 + 1] = q;
    }
}

// =================== BN + exact GELU + channel mix ===================
__global__ __launch_bounds__(256) void bn_gelu_out(const float* __restrict__ fe2,
                                                   const float* __restrict__ partials,
                                                   const float* __restrict__ bn_g,
                                                   const float* __restrict__ bn_b,
                                                   const float* __restrict__ qfto,
                                                   float* __restrict__ out5) {
    int blk = blockIdx.x;  // b*16 + t
    int b = blk / NT_;
    int tid = threadIdx.x;
    float mean[4], rstd[4], gam[4], bet[4], qw[4];
#pragma unroll
    for (int kk = 0; kk < 4; ++kk) {
        float s = 0.f, q = 0.f;
        for (int t2 = 0; t2 < 16; ++t2) {
            const float* p = partials + ((size_t)(b * NT_ + t2) * 8 + kk * 2);
            s += p[0];
            q += p[1];
        }
        float mu = s * (1.f / 12288.f);
        float var = q * (1.f / 12288.f) - mu * mu;
        mean[kk] = mu;
        rstd[kk] = rsqrtf(var + 1e-5f);
        gam[kk] = bn_g[kk];
        bet[kk] = bn_b[kk];
        qw[kk] = qfto[kk];
    }
    for (int l = tid; l < DIM_; l += 256) {
        float acc = 0.f;
#pragma unroll
        for (int kk = 0; kk < 4; ++kk) {
            float v = fe2[((size_t)blk * 4 + kk) * DIM_ + l];
            float nrm = (v - mean[kk]) * rstd[kk] * gam[kk] + bet[kk];
            float ge = 0.5f * nrm * (1.f + erff(nrm * 0.7071067811865475f));
            acc += ge * qw[kk];
        }
        out5[(size_t)blk * DIM_ + l] = acc;
    }
}

// =================== launch ===================
extern "C" void kernel_launch(void* const* d_in, const int* in_sizes, int n_in,
                              void* d_out, int out_size, void* d_ws, size_t ws_size,
                              hipStream_t stream) {
    const float* x      = (const float*)d_in[0];
    const float* tp     = (const float*)d_in[1];
    const float* qkv_w  = (const float*)d_in[2];
    const float* proj_w = (const float*)d_in[3];
    const float* proj_b = (const float*)d_in[4];
    const float* tt_w   = (const float*)d_in[5];
    const float* tt_b   = (const float*)d_in[6];
    const float* tt1_w  = (const float*)d_in[7];
    const float* tt1_b  = (const float*)d_in[8];
    const float* qf_r   = (const float*)d_in[9];
    const float* qf_i   = (const float*)d_in[10];
    const float* qf_j   = (const float*)d_in[11];
    const float* qf_k   = (const float*)d_in[12];
    const float* qf_b   = (const float*)d_in[13];
    const float* dqf_r  = (const float*)d_in[14];
    const float* dqf_i  = (const float*)d_in[15];
    const float* dqf_j  = (const float*)d_in[16];
    const float* dqf_k  = (const float*)d_in[17];
    const float* dqf_b  = (const float*)d_in[18];
    const float* bn_g   = (const float*)d_in[19];
    const float* bn_b   = (const float*)d_in[20];
    const float* qfto   = (const float*)d_in[21];
    float* out = (float*)d_out;
    char* wsb = (char*)d_ws;

    u16* xcb    = (u16*)(wsb + WSO_XCB);
    u16* wqkvb  = (u16*)(wsb + WSO_WQKV);
    u16* wprojb = (u16*)(wsb + WSO_WPROJ);
    u16* qb     = (u16*)(wsb + WSO_QB);
    u16* kb     = (u16*)(wsb + WSO_KB);
    u16* vb     = (u16*)(wsb + WSO_VB);
    u16* vtb    = (u16*)(wsb + WSO_VTB);
    u16* acatb  = (u16*)(wsb + WSO_ACATB);
    u16* tpb    = (u16*)(wsb + WSO_TPB);
    u16* ttwb   = (u16*)(wsb + WSO_TTWB);
    u16* tt1wb  = (u16*)(wsb + WSO_TT1WB);
    u16* chanpb = (u16*)(wsb + WSO_CHANPB);
    float* partb = (float*)(wsb + WSO_PART);
    float* f32r = (float*)(wsb + WSO_F32);
    float* tpout   = f32r + FO_TPOUT;
    float* rawchan = f32r + FO_RAWCHAN;
    float* chpf    = f32r + FO_CHP;
    float* fe2     = f32r + FO_FE2;
    float* stats   = f32r + FO_STATS;

    // all casts (one launch)
    cast_fused<<<5088, 256, 0, stream>>>(tp, x, qkv_w, proj_w, tt_w, tt1_w,
                                         xcb, wqkvb, wprojb, tpb, ttwb, tt1wb);

    // QKV: (8320x768) @ (2304x768)^T -> q,k,v bf16 row-major
    gemm_bf16<0><<<dim3(65, 18, 1), 256, 0, stream>>>(xcb, wqkvb, 768, 768, 768, 0, 0,
                                                      nullptr, nullptr, nullptr, qb, kb, vb, 0);
    // v -> vT
    transpose_v<<<dim3(36, 3, 64), 256, 0, stream>>>(vb, vtb);
    // scores -> raw (output 2, NT) + softmax partials
    gemm_bf16<1><<<dim3(9, 9, 64), 256, 0, stream>>>(qb, kb, 96, 96, 96,
                                                     (size_t)NPAD_ * HD_, (size_t)NPAD_ * HD_,
                                                     nullptr, out + OUT_RAW, partb,
                                                     nullptr, nullptr, nullptr, 0);
    // fused softmax (output 3, NT) + PV -> acat bf16 (64 rows/block)
    attn_pv4<<<dim3(17, 64), 256, 0, stream>>>(out + OUT_RAW, (const float2*)partb,
                                               vtb, out + OUT_ATTN, acatb);
    // proj -> x_out (output 1, NT) + tp_out
    gemm_bf16<2><<<dim3(65, 6, 1), 256, 0, stream>>>(acatb, wprojb, 768, 768, 768, 0, 0,
                                                     proj_b, out + OUT_XOUT, tpout,
                                                     nullptr, nullptr, nullptr, 0);
    // chanp = tp @ tt_w^T + tt_b  (bf16 out)
    gemm_bf16<3><<<dim3(1, 8, 1), 256, 0, stream>>>(tpb, ttwb, 768, 768, 768, 0, 0,
                                                    tt_b, nullptr, nullptr, chanpb, nullptr, nullptr, 1024);
    // windowed channel scores (output 4)
    chan_scores<<<dim3(128, 6), 256, 0, stream>>>(chanpb, x, rawchan, out + OUT_RAWCH);
    // chan softmax (output 5)
    chan_softmax<<<2048, 256, 0, stream>>>(rawchan, out + OUT_ATTNCH);
    // ch_prompts = chanp @ tt1_w^T + tt1_b  (fp32 out)
    gemm_bf16<4><<<dim3(1, 6, 1), 256, 0, stream>>>(chanpb, tt1wb, 1024, 1024, 1024, 0, 0,
                                                    tt1_b, chpf, nullptr, nullptr, nullptr, nullptr, 768);
    // quaternion conv + BN + GELU + mix (output 6)
    quat_conv<<<128, 256, 0, stream>>>(tp, tpout, chpf,
                                       qf_r, qf_i, qf_j, qf_k, qf_b,
                                       dqf_r, dqf_i, dqf_j, dqf_k, dqf_b,
                                       fe2, stats);
    bn_gelu_out<<<128, 256, 0, stream>>>(fe2, stats, bn_g, bn_b, qfto, out + OUT_QOUT);
}

// Round 17
// 487.737 us; speedup vs baseline: 1.0386x; 1.0190x over previous
//
#include <hip/hip_runtime.h>
#include <hip/hip_bf16.h>
#include <math.h>

typedef unsigned short u16;
typedef __attribute__((ext_vector_type(8))) short  bf16x8;
typedef __attribute__((ext_vector_type(4))) float  f32x4;
typedef __attribute__((ext_vector_type(8))) u16    u16x8;
typedef __attribute__((ext_vector_type(4))) u16    u16x4;

// ---------------- problem constants ----------------
#define B_      8
#define NT_     16
#define DIM_    768
#define HEADS_  8
#define HD_     96
#define PIX_    1024
#define NTOK_   1040
#define NPAD_   1152

// ---------------- workspace layout (byte offsets) ----------------
#define WSO_XCB     0ull
#define WSO_WQKV    12779520ull
#define WSO_WPROJ   16318464ull
#define WSO_QB      17498112ull
#define WSO_KB      31653888ull
#define WSO_VB      45809664ull
#define WSO_VTB     59965440ull
#define WSO_ACATB   74121216ull
#define WSO_TPB     86900736ull
#define WSO_TTWB    87097344ull
#define WSO_TT1WB   88670208ull
#define WSO_CHANPB  90243072ull
#define WSO_PART    90505216ull    // (64,9,1152) float2
#define WSO_F32     95813632ull
// fp32 region offsets (floats)
#define FO_TPOUT    0ull           // 98,304
#define FO_RAWCHAN  98304ull       // 1,572,864
#define FO_CHP      1671168ull     // 98,304
#define FO_FE2      1769472ull     // 393,216
#define FO_STATS    2162688ull     // 1024

// ---------------- output layout (float offsets) ----------------
#define OUT_XOUT   0ull
#define OUT_RAW    6291456ull
#define OUT_ATTN   75513856ull
#define OUT_RAWCH  144736256ull
#define OUT_ATTNCH 146309120ull
#define OUT_QOUT   147881984ull

#define SCALE_SPA 0.1020620726159658f   // 96^-0.5

__device__ __forceinline__ u16 f2b(float f) {
    union { float f; unsigned u; } x; x.f = f;
    unsigned r = x.u + 0x7FFFu + ((x.u >> 16) & 1u);
    return (u16)(r >> 16);
}
__device__ __forceinline__ u16 f2b_fast(float f) {
    __hip_bfloat16 h = __float2bfloat16(f);
    return __builtin_bit_cast(u16, h);
}
__device__ __forceinline__ float b2f(u16 h) {
    union { unsigned u; float f; } x; x.u = ((unsigned)h) << 16;
    return x.f;
}

// async global->LDS, 16B per lane, wave-uniform LDS base
__device__ __forceinline__ void gload_lds16(const u16* gsrc, u16* ldst) {
    __builtin_amdgcn_global_load_lds((const __attribute__((address_space(1))) void*)gsrc,
                                     (__attribute__((address_space(3))) void*)ldst,
                                     16, 0, 0);
}

// =================== all casts in one launch (same resource class) ===================
__global__ __launch_bounds__(256) void cast_fused(const float* __restrict__ tp,
                                                  const float* __restrict__ x,
                                                  const float* __restrict__ qkv_w,
                                                  const float* __restrict__ proj_w,
                                                  const float* __restrict__ tt_w,
                                                  const float* __restrict__ tt1_w,
                                                  u16* __restrict__ xcb,
                                                  u16* __restrict__ wqkvb,
                                                  u16* __restrict__ wprojb,
                                                  u16* __restrict__ tpb,
                                                  u16* __restrict__ ttwb,
                                                  u16* __restrict__ tt1wb) {
    int bx = blockIdx.x, tid = threadIdx.x;
    const float* s;
    u16* d8;
    if (bx < 3120) {
        size_t idx8 = ((size_t)bx * 256 + tid) * 8;
        int c = idx8 % DIM_;
        int n = (idx8 / DIM_) % NTOK_;
        int b = idx8 / ((size_t)DIM_ * NTOK_);
        s = (n < NT_) ? tp + ((size_t)b * NT_ + n) * DIM_ + c
                      : x + ((size_t)b * PIX_ + (n - NT_)) * DIM_ + c;
        d8 = xcb + idx8;
    } else {
        int i = (bx - 3120) * 256 + tid;
        const float* src;
        u16* dst;
        int li;
        if (i < 221184)      { src = qkv_w;  dst = wqkvb;  li = i; }
        else if (i < 294912) { src = proj_w; dst = wprojb; li = i - 221184; }
        else if (i < 307200) { src = tp;     dst = tpb;    li = i - 294912; }
        else if (i < 405504) { src = tt_w;   dst = ttwb;   li = i - 307200; }
        else if (i < 503808) { src = tt1_w;  dst = tt1wb;  li = i - 405504; }
        else return;
        s = src + (size_t)li * 8;
        d8 = dst + (size_t)li * 8;
    }
    float4 a = *(const float4*)s;
    float4 d = *(const float4*)(s + 4);
    u16x8 r;
    r[0] = f2b(a.x); r[1] = f2b(a.y); r[2] = f2b(a.z); r[3] = f2b(a.w);
    r[4] = f2b(d.x); r[5] = f2b(d.y); r[6] = f2b(d.z); r[7] = f2b(d.w);
    *(u16x8*)d8 = r;
}

// =================== generic bf16 MFMA GEMM: C = A(MxK) @ W(NxK)^T ===================
// Staging via global_load_lds (16B/lane, linear LDS [128][32]).
// MODE 0: QKV scatter -> q,k,v bf16 row-major (B,H,1152,96)
// MODE 1: scores -> raw fp32 NT-store (guarded) + per-(row,jtile) softmax partials (o1)
// MODE 2: proj(+bias) -> split tp_out(o1)/x_out(o0, NT) fp32
// MODE 3: plain bf16 out (+bias) to oq, stride ldo
// MODE 4: plain fp32 out (+bias) to o0, stride ldo
template <int MODE>
__global__ __launch_bounds__(256) void gemm_bf16(
    const u16* __restrict__ A, const u16* __restrict__ Bw,
    int lda, int ldb, int K, size_t strA, size_t strB,
    const float* __restrict__ bias,
    float* __restrict__ o0, float* __restrict__ o1,
    u16* __restrict__ oq, u16* __restrict__ ok, u16* __restrict__ ov,
    int ldo) {
    __shared__ u16 As[128 * 32];
    __shared__ u16 Bs[128 * 32];
    __shared__ float redm[128][2];
    __shared__ float reds[128][2];
    const int tid = threadIdx.x;
    const int bm = blockIdx.x, bn = blockIdx.y, z = blockIdx.z;
    const u16* Ab = A + strA * z;
    const u16* Bb = Bw + strB * z;
    const int lane = tid & 63, wid = tid >> 6;
    const int ln = lane & 15, hi = lane >> 4;
    const int wr = wid >> 1, wc = wid & 1;
    const int lrow = lane >> 2;          // 0..15 within 16-row group
    const int lcol = (lane & 3) * 8;     // u16 col offset within 32
    f32x4 acc[4][4] = {};
    for (int kt = 0; kt < K; kt += 32) {
        __syncthreads();
#pragma unroll
        for (int t = 0; t < 2; ++t) {
            int rowbase = t * 64 + wid * 16;
            const u16* ga = Ab + (size_t)(bm * 128 + rowbase + lrow) * lda + kt + lcol;
            const u16* gb = Bb + (size_t)(bn * 128 + rowbase + lrow) * ldb + kt + lcol;
            gload_lds16(ga, &As[rowbase * 32]);
            gload_lds16(gb, &Bs[rowbase * 32]);
        }
        __syncthreads();
        bf16x8 af[4], bfr[4];
#pragma unroll
        for (int m = 0; m < 4; ++m)
            af[m] = *(const bf16x8*)&As[(wr * 64 + m * 16 + ln) * 32 + hi * 8];
#pragma unroll
        for (int n = 0; n < 4; ++n)
            bfr[n] = *(const bf16x8*)&Bs[(wc * 64 + n * 16 + ln) * 32 + hi * 8];
#pragma unroll
        for (int m = 0; m < 4; ++m)
#pragma unroll
            for (int n = 0; n < 4; ++n)
                acc[m][n] = __builtin_amdgcn_mfma_f32_16x16x32_bf16(af[m], bfr[n], acc[m][n], 0, 0, 0);
    }
#pragma unroll
    for (int m = 0; m < 4; ++m) {
#pragma unroll
        for (int n = 0; n < 4; ++n) {
#pragma unroll
            for (int j = 0; j < 4; ++j) {
                int gm = bm * 128 + wr * 64 + m * 16 + hi * 4 + j;
                int gn = bn * 128 + wc * 64 + n * 16 + ln;
                float v = acc[m][n][j];
                if (MODE == 0) {
                    int b = gm / NTOK_, nn = gm - b * NTOK_;
                    int s = gn / DIM_, rem = gn - s * DIM_;
                    int h = rem / HD_, d = rem - h * HD_;
                    u16 hv = f2b(v);
                    u16* dst = (s == 0) ? oq : (s == 1) ? ok : ov;
                    dst[(((size_t)b * HEADS_ + h) * NPAD_ + nn) * HD_ + d] = hv;
                } else if (MODE == 1) {
                    if (gm < NTOK_ && gn < NTOK_)
                        __builtin_nontemporal_store(v, &o0[((size_t)z * NTOK_ + gm) * NTOK_ + gn]);
                } else if (MODE == 2) {
                    v += bias[gn];
                    int b = gm / NTOK_, nn = gm - b * NTOK_;
                    if (nn < NT_) o1[((size_t)b * NT_ + nn) * DIM_ + gn] = v;
                    else          __builtin_nontemporal_store(v, &o0[((size_t)b * PIX_ + (nn - NT_)) * DIM_ + gn]);
                } else if (MODE == 3) {
                    oq[(size_t)gm * ldo + gn] = f2b(v + bias[gn]);
                } else {
                    o0[(size_t)gm * ldo + gn] = v + bias[gn];
                }
            }
        }
    }
    if (MODE == 1) {
#pragma unroll
        for (int m = 0; m < 4; ++m) {
#pragma unroll
            for (int j = 0; j < 4; ++j) {
                float v[4];
                float mx = -INFINITY;
#pragma unroll
                for (int n = 0; n < 4; ++n) {
                    int gn = bn * 128 + wc * 64 + n * 16 + ln;
                    v[n] = (gn < NTOK_) ? acc[m][n][j] * SCALE_SPA : -INFINITY;
                    mx = fmaxf(mx, v[n]);
                }
#pragma unroll
                for (int off = 1; off < 16; off <<= 1) mx = fmaxf(mx, __shfl_xor(mx, off));
                float s = 0.f;
                if (mx > -INFINITY) {
#pragma unroll
                    for (int n = 0; n < 4; ++n)
                        if (v[n] > -INFINITY) s += __expf(v[n] - mx);
                }
#pragma unroll
                for (int off = 1; off < 16; off <<= 1) s += __shfl_xor(s, off);
                if (ln == 0) {
                    int row = wr * 64 + m * 16 + hi * 4 + j;
                    redm[row][wc] = mx;
                    reds[row][wc] = s;
                }
            }
        }
        __syncthreads();
        if (tid < 128) {
            float m0 = redm[tid][0], m1 = redm[tid][1];
            float s0 = reds[tid][0], s1 = reds[tid][1];
            float M = fmaxf(m0, m1);
            float S = 0.f;
            if (m0 > -INFINITY) S += s0 * __expf(m0 - M);
            if (m1 > -INFINITY) S += s1 * __expf(m1 - M);
            float2* pp = (float2*)o1;
            pp[((size_t)z * 9 + bn) * NPAD_ + bm * 128 + tid] = make_float2(M, S);
        }
    }
}

// =================== v (B,H,1152,96) -> vT (B,H,96,1152) ===================
__global__ __launch_bounds__(256) void transpose_v(const u16* __restrict__ vb,
                                                   u16* __restrict__ vtb) {
    __shared__ u16 t[32][34];
    int bi = blockIdx.x, bj = blockIdx.y, z = blockIdx.z;
    const u16* ib = vb + (size_t)z * NPAD_ * HD_;
    u16* ob = vtb + (size_t)z * HD_ * NPAD_;
    int tid = threadIdx.x;
    int r = tid >> 3, c = (tid & 7) * 4;
    *(u16x4*)&t[r][c] = *(const u16x4*)(ib + (size_t)(bi * 32 + r) * HD_ + bj * 32 + c);
    __syncthreads();
    u16x4 o;
    o[0] = t[c + 0][r]; o[1] = t[c + 1][r]; o[2] = t[c + 2][r]; o[3] = t[c + 3][r];
    *(u16x4*)(ob + (size_t)(bj * 32 + r) * NPAD_ + bi * 32 + c) = o;
}

// =================== fused softmax + PV, 64 rows/block, T14 prefetch ===================
// NT load raw (stream-once) prefetched one chunk ahead (loads fly under MFMA);
// NT store attn (never re-read). Uniform 9x128-col chunks (guards mask pad cols).
__global__ __launch_bounds__(256) void attn_pv4(const float* __restrict__ raw,
                                                const float2* __restrict__ part,
                                                const u16* __restrict__ vtb,
                                                float* __restrict__ attn,
                                                u16* __restrict__ acat) {
    __shared__ u16 Ps[64][136];
    __shared__ float sm[64], si[64];
    const int tid = threadIdx.x;
    const int bi = blockIdx.x, z = blockIdx.y;
    const int lane = tid & 63, wid = tid >> 6;
    const int ln = lane & 15, hi = lane >> 4;
    const int wr = wid >> 1, wc = wid & 1;
    const int r0 = tid >> 3, c8 = tid & 7;
    const u16* vbz = vtb + (size_t)z * HD_ * NPAD_;
    const float* rawz = raw + (size_t)z * NTOK_ * NTOK_;
    float* attnz = attn + (size_t)z * NTOK_ * NTOK_;
    int rows[2];
    bool vr[2];
#pragma unroll
    for (int p = 0; p < 2; ++p) {
        rows[p] = bi * 64 + p * 32 + r0;
        vr[p] = rows[p] < NTOK_;
    }
    // prologue: issue chunk-0 loads (overlaps the stats combine below)
    f32x4 rcur[4][2], rnxt[4][2];
#pragma unroll
    for (int s = 0; s < 4; ++s) {
        int col = s * 32 + c8 * 4;
#pragma unroll
        for (int p = 0; p < 2; ++p) {
            f32x4 zv = {0.f, 0.f, 0.f, 0.f};
            if (vr[p] && col < NTOK_)
                zv = __builtin_nontemporal_load((const f32x4*)(rawz + (size_t)rows[p] * NTOK_ + col));
            rcur[s][p] = zv;
        }
    }
    if (tid < 64) {
        int grow = bi * 64 + tid;
        float M = -INFINITY;
        float mj[9], sj[9];
#pragma unroll
        for (int jt = 0; jt < 9; ++jt) {
            float2 p = part[((size_t)z * 9 + jt) * NPAD_ + grow];
            mj[jt] = p.x; sj[jt] = p.y;
            M = fmaxf(M, p.x);
        }
        float S = 0.f;
#pragma unroll
        for (int jt = 0; jt < 9; ++jt)
            if (mj[jt] > -INFINITY) S += sj[jt] * __expf(mj[jt] - M);
        sm[tid] = M;
        si[tid] = 1.f / S;
    }
    __syncthreads();
    float mr[2], ir[2];
#pragma unroll
    for (int p = 0; p < 2; ++p) {
        mr[p] = sm[p * 32 + r0];
        ir[p] = si[p * 32 + r0];
    }
    f32x4 oacc[2][3] = {};
    for (int ci = 0; ci < 9; ++ci) {
        const int c0 = ci * 128;
        // phase A: exp + attn NT store + Ps from rcur
#pragma unroll
        for (int s = 0; s < 4; ++s) {
            int cl = s * 32 + c8 * 4;
            int col = c0 + cl;
#pragma unroll
            for (int p = 0; p < 2; ++p) {
                int rr = p * 32 + r0;
                u16x4 pb = {0, 0, 0, 0};
                if (vr[p] && col < NTOK_) {
                    f32x4 v = rcur[s][p];
                    f32x4 pr;
                    pr[0] = __expf(v[0] * SCALE_SPA - mr[p]) * ir[p];
                    pr[1] = __expf(v[1] * SCALE_SPA - mr[p]) * ir[p];
                    pr[2] = __expf(v[2] * SCALE_SPA - mr[p]) * ir[p];
                    pr[3] = __expf(v[3] * SCALE_SPA - mr[p]) * ir[p];
                    __builtin_nontemporal_store(pr, (f32x4*)(attnz + (size_t)rows[p] * NTOK_ + col));
                    pb[0] = f2b_fast(pr[0]); pb[1] = f2b_fast(pr[1]);
                    pb[2] = f2b_fast(pr[2]); pb[3] = f2b_fast(pr[3]);
                }
                *(u16x4*)&Ps[rr][cl] = pb;
            }
        }
        // prefetch next chunk (flies during MFMA phase)
        if (ci < 8) {
#pragma unroll
            for (int s = 0; s < 4; ++s) {
                int col = c0 + 128 + s * 32 + c8 * 4;
#pragma unroll
                for (int p = 0; p < 2; ++p) {
                    f32x4 zv = {0.f, 0.f, 0.f, 0.f};
                    if (vr[p] && col < NTOK_)
                        zv = __builtin_nontemporal_load((const f32x4*)(rawz + (size_t)rows[p] * NTOK_ + col));
                    rnxt[s][p] = zv;
                }
            }
        }
        __syncthreads();
        // phase B: PV MFMA
#pragma unroll
        for (int ktl = 0; ktl < 4; ++ktl) {
            bf16x8 af[2];
#pragma unroll
            for (int m = 0; m < 2; ++m)
                af[m] = *(const bf16x8*)&Ps[wr * 32 + m * 16 + ln][ktl * 32 + hi * 8];
#pragma unroll
            for (int n = 0; n < 3; ++n) {
                bf16x8 bv = *(const bf16x8*)(vbz + (size_t)(wc * 48 + n * 16 + ln) * NPAD_
                                             + c0 + ktl * 32 + hi * 8);
#pragma unroll
                for (int m = 0; m < 2; ++m)
                    oacc[m][n] = __builtin_amdgcn_mfma_f32_16x16x32_bf16(af[m], bv, oacc[m][n], 0, 0, 0);
            }
        }
        __syncthreads();
#pragma unroll
        for (int s = 0; s < 4; ++s)
#pragma unroll
            for (int p = 0; p < 2; ++p)
                rcur[s][p] = rnxt[s][p];
    }
    const int b = z >> 3, h = z & 7;
#pragma unroll
    for (int m = 0; m < 2; ++m)
#pragma unroll
        for (int n = 0; n < 3; ++n)
#pragma unroll
            for (int j = 0; j < 4; ++j) {
                int gi = bi * 64 + wr * 32 + m * 16 + hi * 4 + j;
                if (gi < NTOK_) {
                    int gd = wc * 48 + n * 16 + ln;
                    acat[((size_t)b * NTOK_ + gi) * DIM_ + h * HD_ + gd] = f2b(oacc[m][n][j]);
                }
            }
}

// =================== windowed channel scores (bf16 chanp) ===================
__global__ __launch_bounds__(256) void chan_scores(const u16* __restrict__ chanpb,
                                                   const float* __restrict__ x,
                                                   float* __restrict__ rawchan_ws,
                                                   float* __restrict__ out_raw) {
    int blk = blockIdx.x;  // b*16 + w
    int b = blk / 16, w = blk % 16;
    int cy = blockIdx.y;   // 6 chunks of 8 cc
    int nh = w / 4, nw = w % 4;
    __shared__ float qp[16][65];
    __shared__ float xs[64][17];
    int tid = threadIdx.x;
    for (int l = tid; l < 16 * 64; l += 256) {
        int t = l / 64, d = l % 64;
        int wh = d / 8, ww = d % 8;
        int pix = (nh * 8 + wh) * 32 + nw * 8 + ww;
        qp[t][d] = b2f(chanpb[((size_t)b * NT_ + t) * PIX_ + pix]);
    }
    __syncthreads();
    int t = tid % 16, cl = tid / 16;
    for (int cc = cy * 8; cc < cy * 8 + 8; ++cc) {
        for (int l = tid; l < 64 * 16; l += 256) {
            int d = l / 16, c2 = l % 16;
            int wh = d / 8, ww = d % 8;
            int pix = (nh * 8 + wh) * 32 + nw * 8 + ww;
            xs[d][c2] = x[((size_t)b * PIX_ + pix) * DIM_ + cc * 16 + c2];
        }
        __syncthreads();
        float acc = 0.f;
#pragma unroll
        for (int d = 0; d < 64; ++d) acc += qp[t][d] * xs[d][cl];
        int c = cc * 16 + cl;
        rawchan_ws[(((size_t)b * 16 + w) * NT_ + t) * DIM_ + c] = acc;
        out_raw[(((size_t)b * NT_ + t) * DIM_ + c) * 16 + w] = acc;
        __syncthreads();
    }
}

// =================== chan softmax over c (768), scattered write ===================
__global__ __launch_bounds__(256) void chan_softmax(const float* __restrict__ rawchan_ws,
                                                    float* __restrict__ out_attn) {
    int row = blockIdx.x;  // (b*16+w)*16 + t
    int b = row / 256;
    int w = (row / 16) % 16;
    int t = row % 16;
    const float* rp = rawchan_ws + (size_t)row * DIM_;
    int tid = threadIdx.x;
    float vals[3];
    float m = -INFINITY;
#pragma unroll
    for (int i = 0; i < 3; ++i) {
        vals[i] = rp[tid + i * 256] * 0.125f;
        m = fmaxf(m, vals[i]);
    }
    __shared__ float redm[4], reds[4];
    for (int off = 32; off; off >>= 1) m = fmaxf(m, __shfl_xor(m, off));
    if ((tid & 63) == 0) redm[tid >> 6] = m;
    __syncthreads();
    m = fmaxf(fmaxf(redm[0], redm[1]), fmaxf(redm[2], redm[3]));
    float s = 0.f;
#pragma unroll
    for (int i = 0; i < 3; ++i) { vals[i] = __expf(vals[i] - m); s += vals[i]; }
    for (int off = 32; off; off >>= 1) s += __shfl_xor(s, off);
    if ((tid & 63) == 0) reds[tid >> 6] = s;
    __syncthreads();
    s = reds[0] + reds[1] + reds[2] + reds[3];
    float inv = 1.f / s;
#pragma unroll
    for (int i = 0; i < 3; ++i) {
        int c = tid + i * 256;
        out_attn[(((size_t)b * NT_ + t) * DIM_ + c) * 16 + w] = vals[i] * inv;
    }
}

// =================== quaternion double conv (per (b,t) block) ===================
__global__ __launch_bounds__(256) void quat_conv(const float* __restrict__ tp,
                                                 const float* __restrict__ tpo,
                                                 const float* __restrict__ chp,
                                                 const float* __restrict__ qf_r, const float* __restrict__ qf_i,
                                                 const float* __restrict__ qf_j, const float* __restrict__ qf_k,
                                                 const float* __restrict__ qf_b,
                                                 const float* __restrict__ dqf_r, const float* __restrict__ dqf_i,
                                                 const float* __restrict__ dqf_j, const float* __restrict__ dqf_k,
                                                 const float* __restrict__ dqf_b,
                                                 float* __restrict__ fe2_out,
                                                 float* __restrict__ partials) {
    int blk = blockIdx.x;  // b*16 + t
    int b = blk / NT_, t = blk % NT_;
    __shared__ float w1[8][4][3];
    __shared__ float w2[8][4][3];
    __shared__ float w2c[4][8][3];
    __shared__ float qs[4][770];
    __shared__ float fs[8][770];
    __shared__ float wsum[4][4], wsq[4][4];
    int tid = threadIdx.x;
    if (tid < 96) {
        int o = tid / 12, rest = tid % 12, ic = rest / 3, tap = rest % 3;
        int g = o / 2, oo = o % 2;
        const int   cidx[4][4] = {{0, 1, 2, 3}, {1, 0, 3, 2}, {2, 3, 0, 1}, {3, 2, 1, 0}};
        const float csgn[4][4] = {{1, -1, -1, -1}, {1, 1, -1, 1}, {1, 1, 1, -1}, {1, -1, 1, 1}};
        const float* s1[4] = {qf_r, qf_i, qf_j, qf_k};
        const float* s2[4] = {dqf_r, dqf_i, dqf_j, dqf_k};
        w1[o][ic][tap] = csgn[g][ic] * s1[cidx[g][ic]][oo * 3 + tap];
        w2[o][ic][tap] = csgn[g][ic] * s2[cidx[g][ic]][oo * 3 + tap];
    }
    for (int l = tid; l < DIM_; l += 256) {
        size_t base = ((size_t)b * NT_ + t) * DIM_ + l;
        qs[0][1 + l] = 0.f;
        qs[1][1 + l] = tp[base];
        qs[2][1 + l] = tpo[base];
        qs[3][1 + l] = chp[base];
    }
    if (tid < 4) { qs[tid][0] = 0.f; qs[tid][769] = 0.f; }
    if (tid < 8) { fs[tid][0] = 0.f; fs[tid][769] = 0.f; }
    __syncthreads();
    if (tid < 96) {
        int o2 = tid / 24, rest = tid % 24, i2 = rest / 3, tap = rest % 3;
        w2c[o2][i2][tap] = w2[i2][o2][2 - tap];
    }
    for (int l = tid; l < DIM_; l += 256) {
#pragma unroll
        for (int o = 0; o < 8; ++o) {
            float a = qf_b[o];
#pragma unroll
            for (int ic = 0; ic < 4; ++ic)
#pragma unroll
                for (int tap = 0; tap < 3; ++tap) a += w1[o][ic][tap] * qs[ic][l + tap];
            fs[o][1 + l] = a;
        }
    }
    __syncthreads();
    float lsum[4] = {}, lsq[4] = {};
    for (int l = tid; l < DIM_; l += 256) {
#pragma unroll
        for (int o2 = 0; o2 < 4; ++o2) {
            float a = dqf_b[o2];
#pragma unroll
            for (int i2 = 0; i2 < 8; ++i2)
#pragma unroll
                for (int tap = 0; tap < 3; ++tap) a += w2c[o2][i2][tap] * fs[i2][l + tap];
            fe2_out[((size_t)blk * 4 + o2) * DIM_ + l] = a;
            lsum[o2] += a;
            lsq[o2] += a * a;
        }
    }
    int wid = tid >> 6;
#pragma unroll
    for (int o2 = 0; o2 < 4; ++o2) {
        float s = lsum[o2], q = lsq[o2];
        for (int off = 32; off; off >>= 1) { s += __shfl_xor(s, off); q += __shfl_xor(q, off); }
        if ((tid & 63) == 0) { wsum[wid][o2] = s; wsq[wid][o2] = q; }
    }
    __syncthreads();
    if (tid < 4) {
        float s = wsum[0][tid] + wsum[1][tid] + wsum[2][tid] + wsum[3][tid];
        float q = wsq[0][tid] + wsq[1][tid] + wsq[2][tid] + wsq[3][tid];
        partials[(size_t)blk * 8 + tid * 2 + 0] = s;
        partials[(size_t)blk * 8 + tid * 2 + 1] = q;
    }
}

// =================== BN + exact GELU + channel mix ===================
__global__ __launch_bounds__(256) void bn_gelu_out(const float* __restrict__ fe2,
                                                   const float* __restrict__ partials,
                                                   const float* __restrict__ bn_g,
                                                   const float* __restrict__ bn_b,
                                                   const float* __restrict__ qfto,
                                                   float* __restrict__ out5) {
    int blk = blockIdx.x;  // b*16 + t
    int b = blk / NT_;
    int tid = threadIdx.x;
    float mean[4], rstd[4], gam[4], bet[4], qw[4];
#pragma unroll
    for (int kk = 0; kk < 4; ++kk) {
        float s = 0.f, q = 0.f;
        for (int t2 = 0; t2 < 16; ++t2) {
            const float* p = partials + ((size_t)(b * NT_ + t2) * 8 + kk * 2);
            s += p[0];
            q += p[1];
        }
        float mu = s * (1.f / 12288.f);
        float var = q * (1.f / 12288.f) - mu * mu;
        mean[kk] = mu;
        rstd[kk] = rsqrtf(var + 1e-5f);
        gam[kk] = bn_g[kk];
        bet[kk] = bn_b[kk];
        qw[kk] = qfto[kk];
    }
    for (int l = tid; l < DIM_; l += 256) {
        float acc = 0.f;
#pragma unroll
        for (int kk = 0; kk < 4; ++kk) {
            float v = fe2[((size_t)blk * 4 + kk) * DIM_ + l];
            float nrm = (v - mean[kk]) * rstd[kk] * gam[kk] + bet[kk];
            float ge = 0.5f * nrm * (1.f + erff(nrm * 0.7071067811865475f));
            acc += ge * qw[kk];
        }
        out5[(size_t)blk * DIM_ + l] = acc;
    }
}

// =================== launch ===================
extern "C" void kernel_launch(void* const* d_in, const int* in_sizes, int n_in,
                              void* d_out, int out_size, void* d_ws, size_t ws_size,
                              hipStream_t stream) {
    const float* x      = (const float*)d_in[0];
    const float* tp     = (const float*)d_in[1];
    const float* qkv_w  = (const float*)d_in[2];
    const float* proj_w = (const float*)d_in[3];
    const float* proj_b = (const float*)d_in[4];
    const float* tt_w   = (const float*)d_in[5];
    const float* tt_b   = (const float*)d_in[6];
    const float* tt1_w  = (const float*)d_in[7];
    const float* tt1_b  = (const float*)d_in[8];
    const float* qf_r   = (const float*)d_in[9];
    const float* qf_i   = (const float*)d_in[10];
    const float* qf_j   = (const float*)d_in[11];
    const float* qf_k   = (const float*)d_in[12];
    const float* qf_b   = (const float*)d_in[13];
    const float* dqf_r  = (const float*)d_in[14];
    const float* dqf_i  = (const float*)d_in[15];
    const float* dqf_j  = (const float*)d_in[16];
    const float* dqf_k  = (const float*)d_in[17];
    const float* dqf_b  = (const float*)d_in[18];
    const float* bn_g   = (const float*)d_in[19];
    const float* bn_b   = (const float*)d_in[20];
    const float* qfto   = (const float*)d_in[21];
    float* out = (float*)d_out;
    char* wsb = (char*)d_ws;

    u16* xcb    = (u16*)(wsb + WSO_XCB);
    u16* wqkvb  = (u16*)(wsb + WSO_WQKV);
    u16* wprojb = (u16*)(wsb + WSO_WPROJ);
    u16* qb     = (u16*)(wsb + WSO_QB);
    u16* kb     = (u16*)(wsb + WSO_KB);
    u16* vb     = (u16*)(wsb + WSO_VB);
    u16* vtb    = (u16*)(wsb + WSO_VTB);
    u16* acatb  = (u16*)(wsb + WSO_ACATB);
    u16* tpb    = (u16*)(wsb + WSO_TPB);
    u16* ttwb   = (u16*)(wsb + WSO_TTWB);
    u16* tt1wb  = (u16*)(wsb + WSO_TT1WB);
    u16* chanpb = (u16*)(wsb + WSO_CHANPB);
    float* partb = (float*)(wsb + WSO_PART);
    float* f32r = (float*)(wsb + WSO_F32);
    float* tpout   = f32r + FO_TPOUT;
    float* rawchan = f32r + FO_RAWCHAN;
    float* chpf    = f32r + FO_CHP;
    float* fe2     = f32r + FO_FE2;
    float* stats   = f32r + FO_STATS;

    // all casts (one launch)
    cast_fused<<<5088, 256, 0, stream>>>(tp, x, qkv_w, proj_w, tt_w, tt1_w,
                                         xcb, wqkvb, wprojb, tpb, ttwb, tt1wb);

    // QKV: (8320x768) @ (2304x768)^T -> q,k,v bf16 row-major
    gemm_bf16<0><<<dim3(65, 18, 1), 256, 0, stream>>>(xcb, wqkvb, 768, 768, 768, 0, 0,
                                                      nullptr, nullptr, nullptr, qb, kb, vb, 0);
    // v -> vT
    transpose_v<<<dim3(36, 3, 64), 256, 0, stream>>>(vb, vtb);
    // scores -> raw (output 2, NT) + softmax partials
    gemm_bf16<1><<<dim3(9, 9, 64), 256, 0, stream>>>(qb, kb, 96, 96, 96,
                                                     (size_t)NPAD_ * HD_, (size_t)NPAD_ * HD_,
                                                     nullptr, out + OUT_RAW, partb,
                                                     nullptr, nullptr, nullptr, 0);
    // fused softmax (output 3, NT) + PV -> acat bf16 (64 rows/block, prefetched)
    attn_pv4<<<dim3(17, 64), 256, 0, stream>>>(out + OUT_RAW, (const float2*)partb,
                                               vtb, out + OUT_ATTN, acatb);
    // proj -> x_out (output 1, NT) + tp_out
    gemm_bf16<2><<<dim3(65, 6, 1), 256, 0, stream>>>(acatb, wprojb, 768, 768, 768, 0, 0,
                                                     proj_b, out + OUT_XOUT, tpout,
                                                     nullptr, nullptr, nullptr, 0);
    // chanp = tp @ tt_w^T + tt_b  (bf16 out)
    gemm_bf16<3><<<dim3(1, 8, 1), 256, 0, stream>>>(tpb, ttwb, 768, 768, 768, 0, 0,
                                                    tt_b, nullptr, nullptr, chanpb, nullptr, nullptr, 1024);
    // windowed channel scores (output 4)
    chan_scores<<<dim3(128, 6), 256, 0, stream>>>(chanpb, x, rawchan, out + OUT_RAWCH);
    // chan softmax (output 5)
    chan_softmax<<<2048, 256, 0, stream>>>(rawchan, out + OUT_ATTNCH);
    // ch_prompts = chanp @ tt1_w^T + tt1_b  (fp32 out)
    gemm_bf16<4><<<dim3(1, 6, 1), 256, 0, stream>>>(chanpb, tt1wb, 1024, 1024, 1024, 0, 0,
                                                    tt1_b, chpf, nullptr, nullptr, nullptr, nullptr, 768);
    // quaternion conv + BN + GELU + mix (output 6)
    quat_conv<<<128, 256, 0, stream>>>(tp, tpout, chpf,
                                       qf_r, qf_i, qf_j, qf_k, qf_b,
                                       dqf_r, dqf_i, dqf_j, dqf_k, dqf_b,
                                       fe2, stats);
    bn_gelu_out<<<128, 256, 0, stream>>>(fe2, stats, bn_g, bn_b, qfto, out + OUT_QOUT);
}